// Round 11
// baseline (71.261 us; speedup 1.0000x reference)
//
#include <hip/hip_runtime.h>

// ---------------------------------------------------------------------------
// LearnedBoardEncoder, factorized, LN fused into the gather.
//
// piece_ids in [0,7), color_ids in [0,3): proj = W[c]@piece[p]+b[c] has only
// 21 distinct rows (21 KB — L1-resident). Kernel 1 (21 blocks) computes proj.
// Kernel 2 (wave-per-row, the proven grain): select source row
// (proj[p,c] + square[s], or turn/castle/ep row), layernorm it IN-WAVE
// (fused sum+sumsq butterfly, 6 steps), NT-store the 1 KB output row.
//
// Evidence trail: NT stores −5.4 us (R6 controlled); wave-per-row best grain
// (R1/R3/R5 matrix); 22-block table build serializes LN (R10, −8 us);
// coop fusion store-drains or spills (R8/R9). This removes the ln_table
// kernel + one graph gap + the table round-trip entirely.
// ---------------------------------------------------------------------------

#define DIM 256
#define NPT 7
#define NCOL 3
#define EPSV 1e-5f

typedef float f32x4 __attribute__((ext_vector_type(4)));

// ---- Kernel 1: proj[p*3+c][d] = b[c][d] + sum_k W[c][d][k] * piece_table[p][k]
__global__ void proj_kernel(const float* __restrict__ piece_table,
                            const float* __restrict__ W,
                            const float* __restrict__ bvec,
                            float* __restrict__ proj) {
    int e = blockIdx.x;              // 0..20  (p*3 + c)
    int p = e / NCOL, c = e % NCOL;
    int d = threadIdx.x;             // 0..255
    __shared__ float pt[DIM];
    pt[d] = piece_table[p * DIM + d];
    __syncthreads();
    const float4* w4 = (const float4*)(W + (size_t)c * DIM * DIM + (size_t)d * DIM);
    float acc = bvec[c * DIM + d];
    #pragma unroll 8
    for (int k = 0; k < DIM / 4; ++k) {
        float4 w = w4[k];
        acc += w.x * pt[k * 4 + 0] + w.y * pt[k * 4 + 1]
             + w.z * pt[k * 4 + 2] + w.w * pt[k * 4 + 3];
    }
    proj[e * DIM + d] = acc;
}

// ---- Kernel 2: fused LN-gather. One wave per output row; in-wave layernorm;
// nontemporal f32x4 stores.
__global__ void gather_ln_kernel(const int* __restrict__ piece_ids,
                                 const int* __restrict__ color_ids,
                                 const int* __restrict__ turn,
                                 const int* __restrict__ castling,
                                 const int* __restrict__ ep_file,
                                 const float* __restrict__ proj,
                                 const float* __restrict__ square_table,
                                 const float* __restrict__ turn_table,
                                 const float* __restrict__ castling_table,
                                 const float* __restrict__ ep_table,
                                 const float* __restrict__ gamma,
                                 const float* __restrict__ beta,
                                 float* __restrict__ out,
                                 int nrows) {
    int r = blockIdx.x * 4 + (threadIdx.x >> 6);
    if (r >= nrows) return;
    int lane = threadIdx.x & 63;
    int b = r / 67;
    int t = r - b * 67;

    // Wave-uniform source selection.
    const float* src;
    const float* addp = nullptr;
    if (t >= 3) {
        int s = t - 3;
        int idx = b * 64 + s;
        src  = proj + (size_t)(piece_ids[idx] * NCOL + color_ids[idx]) * DIM;
        addp = square_table + (size_t)s * DIM;
    } else if (t == 0) {
        src = turn_table + (size_t)turn[b] * DIM;
    } else if (t == 1) {
        src = castling_table + (size_t)castling[b] * DIM;
    } else {
        src = ep_table + (size_t)ep_file[b] * DIM;
    }

    float4 x = ((const float4*)src)[lane];
    if (addp) {
        float4 q = ((const float4*)addp)[lane];
        x.x += q.x; x.y += q.y; x.z += q.z; x.w += q.w;
    }

    // Fused sum + sumsq butterfly (6 dependent steps).
    float s1 = x.x + x.y + x.z + x.w;
    float s2 = x.x * x.x + x.y * x.y + x.z * x.z + x.w * x.w;
    #pragma unroll
    for (int m = 1; m < 64; m <<= 1) {
        s1 += __shfl_xor(s1, m, 64);
        s2 += __shfl_xor(s2, m, 64);
    }
    float mu  = s1 * (1.0f / DIM);
    float var = fmaxf(s2 * (1.0f / DIM) - mu * mu, 0.0f);
    float inv = rsqrtf(var + EPSV);

    float4 g  = ((const float4*)gamma)[lane];
    float4 bb = ((const float4*)beta)[lane];
    f32x4 y;
    y.x = (x.x - mu) * inv * g.x + bb.x;
    y.y = (x.y - mu) * inv * g.y + bb.y;
    y.z = (x.z - mu) * inv * g.z + bb.z;
    y.w = (x.w - mu) * inv * g.w + bb.w;
    __builtin_nontemporal_store(y, (f32x4*)(out + (size_t)r * DIM) + lane);
}

extern "C" void kernel_launch(void* const* d_in, const int* in_sizes, int n_in,
                              void* d_out, int out_size, void* d_ws, size_t ws_size,
                              hipStream_t stream) {
    const int*   piece_ids      = (const int*)d_in[0];
    const int*   color_ids      = (const int*)d_in[1];
    const int*   turn           = (const int*)d_in[2];
    const int*   castling       = (const int*)d_in[3];
    const int*   ep_file        = (const int*)d_in[4];
    const float* piece_table    = (const float*)d_in[5];
    const float* W              = (const float*)d_in[6];
    const float* bvec           = (const float*)d_in[7];
    const float* square_table   = (const float*)d_in[8];
    const float* turn_table     = (const float*)d_in[9];
    const float* castling_table = (const float*)d_in[10];
    const float* ep_table       = (const float*)d_in[11];
    const float* gamma          = (const float*)d_in[12];
    const float* beta           = (const float*)d_in[13];
    float* out = (float*)d_out;

    int B = in_sizes[0] / 64;
    int nrows = B * 67;
    float* proj = (float*)d_ws;                  // 21 * 256 floats

    proj_kernel<<<NPT * NCOL, 256, 0, stream>>>(piece_table, W, bvec, proj);
    gather_ln_kernel<<<(nrows + 3) / 4, 256, 0, stream>>>(
        piece_ids, color_ids, turn, castling, ep_file,
        proj, square_table, turn_table, castling_table, ep_table,
        gamma, beta, out, nrows);
}

// Round 12
// 61.981 us; speedup vs baseline: 1.1497x; 1.1497x over previous
//
#include <hip/hip_runtime.h>

// ---------------------------------------------------------------------------
// LearnedBoardEncoder, factorized. R12 = EXACT R6 (62.0 us best) with ONE
// change: XCD-aware bijective swizzle of the gather blockIdx, so each XCD's
// NT write stream covers a CONTIGUOUS 1/8 slice of the output (HBM row/
// channel locality) instead of 4KB-per-32KB round-robin holes.
//
// Evidence trail: NT stores −5.4 us (R6 controlled test); every other gather
// variant (block-per-board R3, 4-row MLP R5, coop R8/R9, table-fusion R10,
// LN-fusion R11) neutral-to-harmful. Wave-per-row load-store-exit is the
// proven grain; this tests the last untouched variable (write locality).
// ---------------------------------------------------------------------------

#define DIM 256
#define NPT 7
#define NCOL 3
#define NROWS_SQ (NPT * NCOL * 64)   // 1344
#define ROW_TURN 1344                // 2 rows
#define ROW_CASTLE 1346              // 16 rows
#define ROW_EP 1362                  // 9 rows
#define NROWS_TOT 1371
#define EPSV 1e-5f
#define NXCD 8

typedef float f32x4 __attribute__((ext_vector_type(4)));

// ---- Kernel A: proj[p*3+c][d] = b[c][d] + sum_k W[c][d][k] * piece_table[p][k]
__global__ void proj_kernel(const float* __restrict__ piece_table,
                            const float* __restrict__ W,
                            const float* __restrict__ bvec,
                            float* __restrict__ proj) {
    int e = blockIdx.x;              // 0..20  (p*3 + c)
    int p = e / NCOL, c = e % NCOL;
    int d = threadIdx.x;             // 0..255
    __shared__ float pt[DIM];
    pt[d] = piece_table[p * DIM + d];
    __syncthreads();
    const float4* w4 = (const float4*)(W + (size_t)c * DIM * DIM + (size_t)d * DIM);
    float acc = bvec[c * DIM + d];
    #pragma unroll 8
    for (int k = 0; k < DIM / 4; ++k) {
        float4 w = w4[k];
        acc += w.x * pt[k * 4 + 0] + w.y * pt[k * 4 + 1]
             + w.z * pt[k * 4 + 2] + w.w * pt[k * 4 + 3];
    }
    proj[e * DIM + d] = acc;
}

// ---- Kernel B: layernorm each of the 1371 distinct rows into `table`.
__global__ void ln_table_kernel(const float* __restrict__ proj,
                                const float* __restrict__ square_table,
                                const float* __restrict__ turn_table,
                                const float* __restrict__ castling_table,
                                const float* __restrict__ ep_table,
                                const float* __restrict__ gamma,
                                const float* __restrict__ beta,
                                float* __restrict__ table) {
    int w = blockIdx.x * 4 + (threadIdx.x >> 6);
    int lane = threadIdx.x & 63;
    if (w >= NROWS_TOT) return;

    float4 x;
    if (w < NROWS_SQ) {
        int p = w / 192;
        int rem = w - p * 192;
        int c = rem >> 6;
        int s = rem & 63;
        float4 a = ((const float4*)(proj + (p * NCOL + c) * DIM))[lane];
        float4 q = ((const float4*)(square_table + s * DIM))[lane];
        x = make_float4(a.x + q.x, a.y + q.y, a.z + q.z, a.w + q.w);
    } else if (w < ROW_CASTLE) {
        x = ((const float4*)(turn_table + (w - ROW_TURN) * DIM))[lane];
    } else if (w < ROW_EP) {
        x = ((const float4*)(castling_table + (w - ROW_CASTLE) * DIM))[lane];
    } else {
        x = ((const float4*)(ep_table + (w - ROW_EP) * DIM))[lane];
    }

    float s = x.x + x.y + x.z + x.w;
    #pragma unroll
    for (int m = 1; m < 64; m <<= 1) s += __shfl_xor(s, m, 64);
    float mu = s * (1.0f / DIM);

    float dx = x.x - mu, dy = x.y - mu, dz = x.z - mu, dw = x.w - mu;
    float v = dx * dx + dy * dy + dz * dz + dw * dw;
    #pragma unroll
    for (int m = 1; m < 64; m <<= 1) v += __shfl_xor(v, m, 64);
    float inv = rsqrtf(v * (1.0f / DIM) + EPSV);

    float4 g = ((const float4*)gamma)[lane];
    float4 bb = ((const float4*)beta)[lane];
    float4 y = make_float4(dx * inv * g.x + bb.x,
                           dy * inv * g.y + bb.y,
                           dz * inv * g.z + bb.z,
                           dw * inv * g.w + bb.w);
    ((float4*)(table + (size_t)w * DIM))[lane] = y;
}

// ---- Kernel C: gather. One wave per output row; NT f32x4 stores; blockIdx
// remapped so each XCD owns a contiguous slice of the output.
__global__ void gather_kernel(const int* __restrict__ piece_ids,
                              const int* __restrict__ color_ids,
                              const int* __restrict__ turn,
                              const int* __restrict__ castling,
                              const int* __restrict__ ep_file,
                              const float* __restrict__ table,
                              float* __restrict__ out,
                              int nrows, int nwg) {
    // Bijective XCD swizzle (m204 form): q=nwg/8, rem=nwg%8.
    int bid = blockIdx.x;
    int q = nwg / NXCD, rem = nwg % NXCD;
    int xcd = bid % NXCD, pos = bid / NXCD;
    int swz = (xcd < rem ? xcd * (q + 1) : rem * (q + 1) + (xcd - rem) * q) + pos;

    int r = swz * 4 + (threadIdx.x >> 6);
    if (r >= nrows) return;
    int lane = threadIdx.x & 63;
    int b = r / 67;
    int t = r - b * 67;
    int row;
    if (t == 0) {
        row = ROW_TURN + turn[b];
    } else if (t == 1) {
        row = ROW_CASTLE + castling[b];
    } else if (t == 2) {
        row = ROW_EP + ep_file[b];
    } else {
        int s = t - 3;
        int idx = b * 64 + s;
        row = piece_ids[idx] * (NCOL * 64) + color_ids[idx] * 64 + s;
    }
    f32x4 v = ((const f32x4*)(table + (size_t)row * DIM))[lane];
    __builtin_nontemporal_store(v, (f32x4*)(out + (size_t)r * DIM) + lane);
}

extern "C" void kernel_launch(void* const* d_in, const int* in_sizes, int n_in,
                              void* d_out, int out_size, void* d_ws, size_t ws_size,
                              hipStream_t stream) {
    const int*   piece_ids      = (const int*)d_in[0];
    const int*   color_ids      = (const int*)d_in[1];
    const int*   turn           = (const int*)d_in[2];
    const int*   castling       = (const int*)d_in[3];
    const int*   ep_file        = (const int*)d_in[4];
    const float* piece_table    = (const float*)d_in[5];
    const float* W              = (const float*)d_in[6];
    const float* bvec           = (const float*)d_in[7];
    const float* square_table   = (const float*)d_in[8];
    const float* turn_table     = (const float*)d_in[9];
    const float* castling_table = (const float*)d_in[10];
    const float* ep_table       = (const float*)d_in[11];
    const float* gamma          = (const float*)d_in[12];
    const float* beta           = (const float*)d_in[13];
    float* out = (float*)d_out;

    int B = in_sizes[0] / 64;
    int nrows = B * 67;
    int nwg = (nrows + 3) / 4;

    float* proj  = (float*)d_ws;                 // 21 * 256 floats
    float* table = proj + NPT * NCOL * DIM;      // 1371 * 256 floats

    proj_kernel<<<NPT * NCOL, 256, 0, stream>>>(piece_table, W, bvec, proj);
    ln_table_kernel<<<(NROWS_TOT + 3) / 4, 256, 0, stream>>>(
        proj, square_table, turn_table, castling_table, ep_table, gamma, beta, table);
    gather_kernel<<<nwg, 256, 0, stream>>>(
        piece_ids, color_ids, turn, castling, ep_file, table, out, nrows, nwg);
}